// Round 7
// baseline (140.160 us; speedup 1.0000x reference)
//
#include <hip/hip_runtime.h>

#define NMOL 16
#define NAT  512
#define NK   27
#define NBLK 1024     // 4 blocks/CU required for the grid barrier; bound(256,4) guarantees it

// Bit-exact float32 constants matching the numpy reference on host:
//   inv_cell diagonal = 1/20 correctly rounded = 0.05f (0x3D4CCCCD)
//   mask: dist<5.0 with correctly-rounded sqrt  <=>  ss < pred(25.0f) = 0x41C7FFFF
#define SSMAX 24.999998092651367f

__device__ __forceinline__ float wrap1(float v) {
    // proj = rn(v*0.05f); coords in [0,20) => proj<1 => woff=0, frac=proj
    // wrapped = rn(frac*20)
    return __fmul_rn(__fmul_rn(v, 0.05f), 20.0f);
}

// Candidate (unique possible) image per component + exact-mask squared distance
// test. Returns kk in 0..26 on hit, 31 on miss.
__device__ __forceinline__ int probe_code(float wx, float wy, float wz,
                                          float wjx, float wjy, float wjz,
                                          bool self) {
    float dx = __fsub_rn(wx, wjx);
    float dy = __fsub_rn(wy, wjy);
    float dz = __fsub_rn(wz, wjz);
    int ox = (dx > 15.0f) ? -1 : ((dx < -15.0f) ? 1 : 0);
    int oy = (dy > 15.0f) ? -1 : ((dy < -15.0f) ? 1 : 0);
    int oz = (dz > 15.0f) ? -1 : ((dz < -15.0f) ? 1 : 0);
    float ax = __fadd_rn(dx, 20.0f * (float)ox);
    float ay = __fadd_rn(dy, 20.0f * (float)oy);
    float az = __fadd_rn(dz, 20.0f * (float)oz);
    float ss = __fadd_rn(__fadd_rn(__fmul_rn(ax, ax), __fmul_rn(ay, ay)),
                         __fmul_rn(az, az));
    bool hit = (ss < SSMAX) && !self;
    return hit ? ((ox + 1) * 9 + (oy + 1) * 3 + (oz + 1)) : 31;
}

// Single fused kernel. Block = (m, b) owns atoms [8b, 8b+8) of molecule m
// (R2/R5-verified mapping). Phase 1 counts into LDS + caches probe codes in
// registers (R1-verified). Cross-block exchange: per-block per-k subtotals
// (sub) + grand totals (blkmol), published through a HIERARCHICAL grid
// barrier: 64 arrivals on each of 16 padded per-molecule counters (parallel,
// 64-deep serialization only) -> last arriver bumps one gate; everyone polls
// the gate read-only. R1's pathology (1024 RMWs on ONE line) is avoided.
__global__ __launch_bounds__(256, 4) void fused(const float* __restrict__ coords,
                                                int* __restrict__ bar,     // [16*32] arr + gate @512
                                                int* __restrict__ sub,     // [16*27*64]
                                                int* __restrict__ blkmol,  // [1024]
                                                float* __restrict__ out, int P) {
    __shared__ float rr[NAT * 3];
    __shared__ int cur[2][4][NK];      // counts (ph1) -> cursors (emit)
    __shared__ int strip[8][NK];       // per-atom counts snapshot
    __shared__ int ctot[NK], cpre[NK], kexcl[NK];
    __shared__ int tls[NMOL];

    const int blk  = blockIdx.x;
    const int m    = blk >> 6;         // 64 blocks per molecule
    const int b    = blk & 63;
    const int g0   = b * 2;
    const int t    = threadIdx.x;
    const int w    = t >> 6;
    const int lane = t & 63;
    const int iA   = g0 * 4 + w;
    const int iB   = iA + 4;

    // ---- stage raw packed coords + zero counts ----
    const float4* cm4 = reinterpret_cast<const float4*>(coords + (size_t)m * NAT * 3);
    float4* rr4 = reinterpret_cast<float4*>(rr);
    rr4[t] = cm4[t];
    if (t < 128) rr4[t + 256] = cm4[t + 256];
    if (t < 2 * 4 * NK) ((int*)cur)[t] = 0;
    __syncthreads();

    const float wAx = wrap1(rr[iA*3+0]), wAy = wrap1(rr[iA*3+1]), wAz = wrap1(rr[iA*3+2]);
    const float wBx = wrap1(rr[iB*3+0]), wBy = wrap1(rr[iB*3+1]), wBz = wrap1(rr[iB*3+2]);

    // ---- phase 1: probe, count, cache codes (byte per j-iter: kk or 31) ----
    unsigned long long codeA = 0, codeB = 0;
    #pragma unroll
    for (int it = 0; it < NAT / 64; ++it) {
        const int j = it * 64 + lane;
        const float wjx = wrap1(rr[j*3+0]);
        const float wjy = wrap1(rr[j*3+1]);
        const float wjz = wrap1(rr[j*3+2]);
        int cA = probe_code(wAx, wAy, wAz, wjx, wjy, wjz, j == iA);
        int cB = probe_code(wBx, wBy, wBz, wjx, wjy, wjz, j == iB);
        codeA |= (unsigned long long)cA << (8 * it);
        codeB |= (unsigned long long)cB << (8 * it);
        if (cA != 31) atomicAdd(&cur[0][w][cA], 1);
        if (cB != 31) atomicAdd(&cur[1][w][cB], 1);
    }
    __syncthreads();

    // ---- publish summaries (plain stores; flushed by the release below) ----
    if (t < NK) {                       // per-k block subtotal (R5-verified)
        int s = 0;
        #pragma unroll
        for (int uu = 0; uu < 2; ++uu)
            #pragma unroll
            for (int ww = 0; ww < 4; ++ww) s += cur[uu][ww][t];
        sub[(m * NK + t) * 64 + b] = s;
    }
    if (w == 0) {                       // block grand total (R5-verified reduce)
        int s = 0;
        #pragma unroll
        for (int x = lane; x < 216; x += 64) s += ((int*)cur)[x];
        #pragma unroll
        for (int d = 1; d < 64; d <<= 1) s += __shfl_xor(s, d, 64);
        if (lane == 0) blkmol[blk] = s;
    }
    __syncthreads();                    // all waves' stores drained before release

    // ---- hierarchical grid barrier ----
    if (t == 0) {
        // arrival: 64-deep RMW chain per molecule, 16 lines in parallel
        int prev = __hip_atomic_fetch_add(&bar[m * 32], 1,
                                          __ATOMIC_ACQ_REL, __HIP_MEMORY_SCOPE_AGENT);
        if (prev == 63)                 // last of molecule -> bump gate (16 RMWs total)
            __hip_atomic_fetch_add(&bar[512], 1,
                                   __ATOMIC_ACQ_REL, __HIP_MEMORY_SCOPE_AGENT);
        while (__hip_atomic_load(&bar[512], __ATOMIC_ACQUIRE,
                                 __HIP_MEMORY_SCOPE_AGENT) < NMOL)
            __builtin_amdgcn_s_sleep(8);
    }
    __syncthreads();

    // ---- cursor build from summaries (R5-verified decomposition) ----
    for (int mm = w; mm < NMOL; mm += 4) {          // molecule totals
        int v = blkmol[mm * 64 + lane];
        #pragma unroll
        for (int d = 1; d < 64; d <<= 1) v += __shfl_xor(v, d, 64);
        if (lane == 0) tls[mm] = v;
    }
    for (int k = w; k < NK; k += 4) {               // chunk totals + block prefix
        int v = sub[(m * NK + k) * 64 + lane];
        int incl = v;
        #pragma unroll
        for (int d = 1; d < 64; d <<= 1) {
            int u = __shfl_up(incl, d, 64);
            if (lane >= d) incl += u;
        }
        int tot   = __shfl(incl, 63, 64);
        int exclb = __shfl(incl - v, b, 64);
        if (lane == 0) { ctot[k] = tot; cpre[k] = exclb; }
    }
    if (t < 216) {                                  // snapshot own counts
        int uu = t / 108, rem = t % 108, ww = rem / 27, k = rem % 27;
        strip[uu * 4 + ww][k] = cur[uu][ww][k];
    }
    __syncthreads();
    if (t == 0) {
        int run = 0;
        for (int mm = 0; mm < m; ++mm) run += tls[mm];     // molecule base
        for (int k = 0; k < NK; ++k) { kexcl[k] = run; run += ctot[k]; }
    }
    __syncthreads();
    if (t < 216) {                                  // global cursor per (k, own atom)
        int uu = t / 108, rem = t % 108, ww = rem / 27, k = rem % 27;
        int a = uu * 4 + ww;
        int ip = 0;
        for (int a2 = 0; a2 < a; ++a2) ip += strip[a2][k];
        cur[uu][ww][k] = kexcl[k] + cpre[k] + ip;
    }
    __syncthreads();

    // ---- emit from cached codes (R1-verified decode-emit) ----
    const float rAx = rr[iA*3+0], rAy = rr[iA*3+1], rAz = rr[iA*3+2];
    const float rBx = rr[iB*3+0], rBy = rr[iB*3+1], rBz = rr[iB*3+2];
    const unsigned long long ltmask =
        (lane == 0) ? 0ull : (~0ull >> (64 - lane));

    #pragma unroll
    for (int uu = 0; uu < 2; ++uu) {
        const int i  = (uu == 0) ? iA : iB;
        const float rx = (uu == 0) ? rAx : rBx;
        const float ry = (uu == 0) ? rAy : rBy;
        const float rz = (uu == 0) ? rAz : rBz;
        const unsigned long long code8 = (uu == 0) ? codeA : codeB;
        const int pf = m * NAT + i;

        #pragma unroll
        for (int it = 0; it < NAT / 64; ++it) {
            const int j = it * 64 + lane;
            int code = (int)((code8 >> (8 * it)) & 0xffull);
            bool hit = (code != 31);
            int kk = hit ? code : 0;

            // match-any over 5-bit kk among hitting lanes
            unsigned long long grp = __ballot(hit);
            #pragma unroll
            for (int bb = 0; bb < 5; ++bb) {
                unsigned long long bm = __ballot((kk >> bb) & 1);
                grp &= ((kk >> bb) & 1) ? bm : ~bm;
            }
            int leader = hit ? (__ffsll((unsigned long long)grp) - 1) : 0;
            int cntg   = __popcll(grp);
            int rank   = __popcll(grp & ltmask);

            int base = 0;
            if (hit && lane == leader)
                base = atomicAdd(&cur[uu][w][kk], cntg);   // ds_add_rtn cursor
            base = __shfl(base, leader, 64);               // broadcast from leader

            if (hit) {
                int p = base + rank;
                if (p < P) {
                    int ox = kk / 9;
                    int rem = kk - ox * 9;
                    int oy = rem / 3;
                    int oz = rem - oy * 3;
                    ox -= 1; oy -= 1; oz -= 1;
                    float cx = 20.0f * (float)ox;
                    float cy = 20.0f * (float)oy;
                    float cz = 20.0f * (float)oz;
                    const float rjx = rr[j*3+0], rjy = rr[j*3+1], rjz = rr[j*3+2];
                    float px = __fadd_rn(__fsub_rn(rx, rjx), cx);
                    float py = __fadd_rn(__fsub_rn(ry, rjy), cy);
                    float pz = __fadd_rn(__fsub_rn(rz, rjz), cz);
                    float ss = __fadd_rn(__fadd_rn(__fmul_rn(px, px), __fmul_rn(py, py)),
                                         __fmul_rn(pz, pz));
                    out[p]                 = __fsqrt_rn(ss);        // distflat2
                    out[P + p]             = (float)pf;             // pair_first
                    out[2 * P + p]         = (float)(m * NAT + j);  // pair_second
                    out[3 * P + 3 * p + 0] = px;                    // paircoord
                    out[3 * P + 3 * p + 1] = py;
                    out[3 * P + 3 * p + 2] = pz;
                    out[6 * P + 3 * p + 0] = (float)ox;             // offsets
                    out[6 * P + 3 * p + 1] = (float)oy;
                    out[6 * P + 3 * p + 2] = (float)oz;
                    out[9 * P + p]         = (float)kk;             // offset_index
                }
            }
        }
    }
}

extern "C" void kernel_launch(void* const* d_in, const int* in_sizes, int n_in,
                              void* d_out, int out_size, void* d_ws, size_t ws_size,
                              hipStream_t stream) {
    (void)in_sizes; (void)n_in; (void)ws_size;
    const float* coords = (const float*)d_in[0];
    int* bar    = (int*)d_ws;              // 16 arrival counters (128B apart) + gate @512
    int* sub    = bar + 1024;              // 16*27*64 ints
    int* blkmol = sub + NMOL * NK * 64;    // 1024 ints
    float* out  = (float*)d_out;
    const int P = out_size / 10;

    hipMemsetAsync(bar, 0, 4096, stream);  // zero barrier state (ws is poisoned)
    hipLaunchKernelGGL(fused, dim3(NBLK), dim3(256), 0, stream,
                       bar ? coords : coords, bar, sub, blkmol, out, P);
}

// Round 8
// 101.305 us; speedup vs baseline: 1.3835x; 1.3835x over previous
//
#include <hip/hip_runtime.h>

#define NMOL 16
#define NAT  512
#define NK   27
#define NBLK 1024     // 4 blocks/CU; bound(256,4) guarantees co-residency with margin

// Bit-exact float32 constants matching the numpy reference on host:
//   inv_cell diagonal = 1/20 correctly rounded = 0.05f (0x3D4CCCCD)
//   mask: dist<5.0 with correctly-rounded sqrt  <=>  ss < pred(25.0f) = 0x41C7FFFF
#define SSMAX 24.999998092651367f

#define LD_RLX(p)    __hip_atomic_load((p), __ATOMIC_RELAXED, __HIP_MEMORY_SCOPE_AGENT)
#define ST_RLX(p, v) __hip_atomic_store((p), (v), __ATOMIC_RELAXED, __HIP_MEMORY_SCOPE_AGENT)

__device__ __forceinline__ float wrap1(float v) {
    // proj = rn(v*0.05f); coords in [0,20) => proj<1 => woff=0, frac=proj
    // wrapped = rn(frac*20)
    return __fmul_rn(__fmul_rn(v, 0.05f), 20.0f);
}

// Candidate (unique possible) image per component + exact-mask squared distance
// test. Returns kk in 0..26 on hit, 31 on miss.
__device__ __forceinline__ int probe_code(float wx, float wy, float wz,
                                          float wjx, float wjy, float wjz,
                                          bool self) {
    float dx = __fsub_rn(wx, wjx);
    float dy = __fsub_rn(wy, wjy);
    float dz = __fsub_rn(wz, wjz);
    int ox = (dx > 15.0f) ? -1 : ((dx < -15.0f) ? 1 : 0);
    int oy = (dy > 15.0f) ? -1 : ((dy < -15.0f) ? 1 : 0);
    int oz = (dz > 15.0f) ? -1 : ((dz < -15.0f) ? 1 : 0);
    float ax = __fadd_rn(dx, 20.0f * (float)ox);
    float ay = __fadd_rn(dy, 20.0f * (float)oy);
    float az = __fadd_rn(dz, 20.0f * (float)oz);
    float ss = __fadd_rn(__fadd_rn(__fmul_rn(ax, ax), __fmul_rn(ay, ay)),
                         __fmul_rn(az, az));
    bool hit = (ss < SSMAX) && !self;
    return hit ? ((ox + 1) * 9 + (oy + 1) * 3 + (oz + 1)) : 31;
}

// Single fused kernel, ALL cross-block traffic via RELAXED agent atomics.
// Relaxed agent ops are coherent at the Infinity-Cache point WITHOUT the
// per-XCD L2 writeback/invalidate that release/acquire emit (R7's ~55us
// stall). Ordering: each wave's __syncthreads() drains vmcnt, so all of a
// block's summary atomic-stores have completed at the coherence point
// before thread 0's arrival fetch_add issues; consumers read summaries
// (atomic relaxed loads, bypassing local L2) only after the gate reads 16.
__global__ __launch_bounds__(256, 4) void fused(const float* __restrict__ coords,
                                                int* __restrict__ bar,     // [16*32] arrivals + gate @512
                                                int* __restrict__ sub,     // [16*27*64]
                                                int* __restrict__ blkmol,  // [1024]
                                                float* __restrict__ out, int P) {
    __shared__ float rr[NAT * 3];
    __shared__ int cur[2][4][NK];      // counts (ph1) -> cursors (emit)
    __shared__ int strip[8][NK];       // per-atom counts snapshot
    __shared__ int ctot[NK], cpre[NK], kexcl[NK];
    __shared__ int tls[NMOL];

    const int blk  = blockIdx.x;
    const int m    = blk >> 6;         // 64 blocks per molecule
    const int b    = blk & 63;
    const int g0   = b * 2;
    const int t    = threadIdx.x;
    const int w    = t >> 6;
    const int lane = t & 63;
    const int iA   = g0 * 4 + w;
    const int iB   = iA + 4;

    // ---- stage raw packed coords + zero counts ----
    const float4* cm4 = reinterpret_cast<const float4*>(coords + (size_t)m * NAT * 3);
    float4* rr4 = reinterpret_cast<float4*>(rr);
    rr4[t] = cm4[t];
    if (t < 128) rr4[t + 256] = cm4[t + 256];
    if (t < 2 * 4 * NK) ((int*)cur)[t] = 0;
    __syncthreads();

    const float wAx = wrap1(rr[iA*3+0]), wAy = wrap1(rr[iA*3+1]), wAz = wrap1(rr[iA*3+2]);
    const float wBx = wrap1(rr[iB*3+0]), wBy = wrap1(rr[iB*3+1]), wBz = wrap1(rr[iB*3+2]);

    // ---- phase 1: probe, count, cache codes (byte per j-iter: kk or 31) ----
    unsigned long long codeA = 0, codeB = 0;
    #pragma unroll
    for (int it = 0; it < NAT / 64; ++it) {
        const int j = it * 64 + lane;
        const float wjx = wrap1(rr[j*3+0]);
        const float wjy = wrap1(rr[j*3+1]);
        const float wjz = wrap1(rr[j*3+2]);
        int cA = probe_code(wAx, wAy, wAz, wjx, wjy, wjz, j == iA);
        int cB = probe_code(wBx, wBy, wBz, wjx, wjy, wjz, j == iB);
        codeA |= (unsigned long long)cA << (8 * it);
        codeB |= (unsigned long long)cB << (8 * it);
        if (cA != 31) atomicAdd(&cur[0][w][cA], 1);
        if (cB != 31) atomicAdd(&cur[1][w][cB], 1);
    }
    __syncthreads();

    // ---- publish summaries as RELAXED agent atomic stores (write-through) ----
    if (t < NK) {                       // per-k block subtotal (R5-verified sums)
        int s = 0;
        #pragma unroll
        for (int uu = 0; uu < 2; ++uu)
            #pragma unroll
            for (int ww = 0; ww < 4; ++ww) s += cur[uu][ww][t];
        ST_RLX(&sub[(m * NK + t) * 64 + b], s);
    }
    if (w == 0) {                       // block grand total (R5-verified reduce)
        int s = 0;
        #pragma unroll
        for (int x = lane; x < 216; x += 64) s += ((int*)cur)[x];
        #pragma unroll
        for (int d = 1; d < 64; d <<= 1) s += __shfl_xor(s, d, 64);
        if (lane == 0) ST_RLX(&blkmol[blk], s);
    }
    __syncthreads();                    // vmcnt(0) per wave: stores complete at IF$

    // ---- grid gate: relaxed arrivals (16 parallel lines), relaxed polling ----
    if (t == 0) {
        int prev = __hip_atomic_fetch_add(&bar[m * 32], 1,
                                          __ATOMIC_RELAXED, __HIP_MEMORY_SCOPE_AGENT);
        if (prev == 63)                 // last of molecule -> bump single gate
            __hip_atomic_fetch_add(&bar[512], 1,
                                   __ATOMIC_RELAXED, __HIP_MEMORY_SCOPE_AGENT);
        while (LD_RLX(&bar[512]) < NMOL)
            __builtin_amdgcn_s_sleep(2);
    }
    __syncthreads();
    asm volatile("" ::: "memory");      // no hoisting of summary reads above gate

    // ---- cursor build from summaries (R5-verified decomposition) ----
    for (int mm = w; mm < NMOL; mm += 4) {          // molecule totals
        int v = LD_RLX(&blkmol[mm * 64 + lane]);
        #pragma unroll
        for (int d = 1; d < 64; d <<= 1) v += __shfl_xor(v, d, 64);
        if (lane == 0) tls[mm] = v;
    }
    for (int k = w; k < NK; k += 4) {               // chunk totals + block prefix
        int v = LD_RLX(&sub[(m * NK + k) * 64 + lane]);
        int incl = v;
        #pragma unroll
        for (int d = 1; d < 64; d <<= 1) {
            int u = __shfl_up(incl, d, 64);
            if (lane >= d) incl += u;
        }
        int tot   = __shfl(incl, 63, 64);
        int exclb = __shfl(incl - v, b, 64);
        if (lane == 0) { ctot[k] = tot; cpre[k] = exclb; }
    }
    if (t < 216) {                                  // snapshot own counts
        int uu = t / 108, rem = t % 108, ww = rem / 27, k = rem % 27;
        strip[uu * 4 + ww][k] = cur[uu][ww][k];
    }
    __syncthreads();
    if (t == 0) {
        int run = 0;
        for (int mm = 0; mm < m; ++mm) run += tls[mm];     // molecule base
        for (int k = 0; k < NK; ++k) { kexcl[k] = run; run += ctot[k]; }
    }
    __syncthreads();
    if (t < 216) {                                  // global cursor per (k, own atom)
        int uu = t / 108, rem = t % 108, ww = rem / 27, k = rem % 27;
        int a = uu * 4 + ww;
        int ip = 0;
        for (int a2 = 0; a2 < a; ++a2) ip += strip[a2][k];
        cur[uu][ww][k] = kexcl[k] + cpre[k] + ip;
    }
    __syncthreads();

    // ---- emit from cached codes (R1-verified decode-emit) ----
    const float rAx = rr[iA*3+0], rAy = rr[iA*3+1], rAz = rr[iA*3+2];
    const float rBx = rr[iB*3+0], rBy = rr[iB*3+1], rBz = rr[iB*3+2];
    const unsigned long long ltmask =
        (lane == 0) ? 0ull : (~0ull >> (64 - lane));

    #pragma unroll
    for (int uu = 0; uu < 2; ++uu) {
        const int i  = (uu == 0) ? iA : iB;
        const float rx = (uu == 0) ? rAx : rBx;
        const float ry = (uu == 0) ? rAy : rBy;
        const float rz = (uu == 0) ? rAz : rBz;
        const unsigned long long code8 = (uu == 0) ? codeA : codeB;
        const int pf = m * NAT + i;

        #pragma unroll
        for (int it = 0; it < NAT / 64; ++it) {
            const int j = it * 64 + lane;
            int code = (int)((code8 >> (8 * it)) & 0xffull);
            bool hit = (code != 31);
            int kk = hit ? code : 0;

            // match-any over 5-bit kk among hitting lanes
            unsigned long long grp = __ballot(hit);
            #pragma unroll
            for (int bb = 0; bb < 5; ++bb) {
                unsigned long long bm = __ballot((kk >> bb) & 1);
                grp &= ((kk >> bb) & 1) ? bm : ~bm;
            }
            int leader = hit ? (__ffsll((unsigned long long)grp) - 1) : 0;
            int cntg   = __popcll(grp);
            int rank   = __popcll(grp & ltmask);

            int base = 0;
            if (hit && lane == leader)
                base = atomicAdd(&cur[uu][w][kk], cntg);   // ds_add_rtn cursor
            base = __shfl(base, leader, 64);               // broadcast from leader

            if (hit) {
                int p = base + rank;
                if (p < P) {
                    int ox = kk / 9;
                    int rem = kk - ox * 9;
                    int oy = rem / 3;
                    int oz = rem - oy * 3;
                    ox -= 1; oy -= 1; oz -= 1;
                    float cx = 20.0f * (float)ox;
                    float cy = 20.0f * (float)oy;
                    float cz = 20.0f * (float)oz;
                    const float rjx = rr[j*3+0], rjy = rr[j*3+1], rjz = rr[j*3+2];
                    float px = __fadd_rn(__fsub_rn(rx, rjx), cx);
                    float py = __fadd_rn(__fsub_rn(ry, rjy), cy);
                    float pz = __fadd_rn(__fsub_rn(rz, rjz), cz);
                    float ss = __fadd_rn(__fadd_rn(__fmul_rn(px, px), __fmul_rn(py, py)),
                                         __fmul_rn(pz, pz));
                    out[p]                 = __fsqrt_rn(ss);        // distflat2
                    out[P + p]             = (float)pf;             // pair_first
                    out[2 * P + p]         = (float)(m * NAT + j);  // pair_second
                    out[3 * P + 3 * p + 0] = px;                    // paircoord
                    out[3 * P + 3 * p + 1] = py;
                    out[3 * P + 3 * p + 2] = pz;
                    out[6 * P + 3 * p + 0] = (float)ox;             // offsets
                    out[6 * P + 3 * p + 1] = (float)oy;
                    out[6 * P + 3 * p + 2] = (float)oz;
                    out[9 * P + p]         = (float)kk;             // offset_index
                }
            }
        }
    }
}

extern "C" void kernel_launch(void* const* d_in, const int* in_sizes, int n_in,
                              void* d_out, int out_size, void* d_ws, size_t ws_size,
                              hipStream_t stream) {
    (void)in_sizes; (void)n_in; (void)ws_size;
    const float* coords = (const float*)d_in[0];
    int* bar    = (int*)d_ws;              // 16 arrival counters (128B apart) + gate @512
    int* sub    = bar + 1024;              // 16*27*64 ints
    int* blkmol = sub + NMOL * NK * 64;    // 1024 ints
    float* out  = (float*)d_out;
    const int P = out_size / 10;

    hipMemsetAsync(bar, 0, 4096, stream);  // zero barrier state (ws is poisoned)
    hipLaunchKernelGGL(fused, dim3(NBLK), dim3(256), 0, stream,
                       coords, bar, sub, blkmol, out, P);
}